// Round 2
// baseline (617.504 us; speedup 1.0000x reference)
//
#include <hip/hip_runtime.h>
#include <math.h>

// W=4096, D=768, K=768, SPAN=3D=2304, F=20, H=1000, PAIR=6932, C=50.
#define WTOK 4096
#define DD   768
#define KK   768
#define SPAN 2304
#define HH   1000
#define CC   50
#define NPAD 1024   // HH padded for pair-GEMM tiles
#define NBIG 4352   // 2304 (coarse) + 1024 (tgt) + 1024 (ant)
#define PROWS (KK * CC)          // 38400 pair rows

typedef __attribute__((ext_vector_type(8))) short bf16x8;
typedef __attribute__((ext_vector_type(4))) float f32x4;
typedef unsigned short ushort;
typedef unsigned int uint;

__device__ __forceinline__ int bucketd(int d) {
  int l = (d >= 1) ? (31 - __clz(d)) : 0;
  int v = (d <= 4) ? d : (l + 3);
  return min(max(v, 0), 9);
}
__device__ __forceinline__ ushort f2bf(float f) {
  uint u = __float_as_uint(f);
  return (ushort)((u + 0x7fffu + ((u >> 16) & 1u)) >> 16);  // RNE
}
// packed bf16x2 elementwise product, truncating round
__device__ __forceinline__ uint pkmul_t(uint a, uint b) {
  float lo = __uint_as_float(a << 16) * __uint_as_float(b << 16);
  float hi = __uint_as_float(a & 0xffff0000u) * __uint_as_float(b & 0xffff0000u);
  return (__float_as_uint(lo) >> 16) | (__float_as_uint(hi) & 0xffff0000u);
}
__device__ __forceinline__ uint4 pkmul4(uint4 a, uint4 b) {
  uint4 r;
  r.x = pkmul_t(a.x, b.x); r.y = pkmul_t(a.y, b.y);
  r.z = pkmul_t(a.z, b.z); r.w = pkmul_t(a.w, b.w);
  return r;
}
// async global->LDS DMA, 16 B per lane; LDS dest = firstlane base + lane*16
__device__ __forceinline__ void dma16(const ushort* g, ushort* l) {
  __builtin_amdgcn_global_load_lds(
      (const __attribute__((address_space(1))) void*)g,
      (__attribute__((address_space(3))) void*)l, 16, 0, 0);
}

// ---------------------------------------------------------------------------
// K0: fused prep: transposes (k-tiled), dist setup, slow init.
// W1simT now emitted in the 8-phase pair-GEMM layout:
//   [36 ksteps][NPAD rows][64 k] bf16 with bank-swizzle baked into DRAM:
//   physical 16B slot ps holds logical k-slot ls = ps ^ (row & 7).
// ---------------------------------------------------------------------------
#define PB_COARSE 5184
#define PB_W 2304
#define PB_SETUP_BASE (PB_COARSE + 3 * PB_W)          // 12096
#define PB_SLOW_BASE  (PB_SETUP_BASE + 40)            // 12136
#define PB_TOTAL      (PB_SLOW_BASE + 150)            // 12286

__global__ __launch_bounds__(256) void prep_k(
    const float* __restrict__ coarse_w, const float* __restrict__ W1,
    const float* __restrict__ dist_prior, const float* __restrict__ dist_w,
    const float* __restrict__ dist_b, const float* __restrict__ top_dist,
    ushort* __restrict__ BigT, ushort* __restrict__ W1simT,
    float* __restrict__ dist_score, float* __restrict__ Pdist,
    float* __restrict__ slow)
{
  int bid = blockIdx.x;
  int tid = threadIdx.x;
  if (bid >= PB_SLOW_BASE) {
    int t = (bid - PB_SLOW_BASE) * 256 + tid;
    if (t < KK * CC) slow[t] = 0.f;
    return;
  }
  if (bid >= PB_SETUP_BASE) {
    int t = (bid - PB_SETUP_BASE) * 256 + tid;
    if (t < 10) {
      float s = dist_b[0];
      for (int f = 0; f < 20; ++f) s += dist_prior[t * 20 + f] * dist_w[f];
      dist_score[t] = s;
    }
    if (t < 10 * HH) {
      int b = t / HH, h = t % HH;
      float s = 0.f;
      for (int f = 0; f < 20; ++f)
        s += top_dist[b * 20 + f] * W1[(long)(6912 + f) * HH + h];
      Pdist[t] = s;
    }
    return;
  }
  const float* in; int ldin, Cin, nbase, NBrows; ushort* out; int idx;
  int xt; bool bk64 = false;
  if (bid < PB_COARSE) {
    idx = bid; in = coarse_w; ldin = SPAN; Cin = SPAN; nbase = 0;
    NBrows = NBIG; out = BigT; xt = SPAN / 32;
  } else {
    idx = bid - PB_COARSE;
    int region = idx / PB_W;  // 0=tgt 1=ant 2=sim
    idx = idx % PB_W;
    if (region == 0) { in = W1; nbase = 2304; NBrows = NBIG; out = BigT; }
    else if (region == 1) { in = W1 + (size_t)SPAN * HH; nbase = 3328; NBrows = NBIG; out = BigT; }
    else { in = W1 + (size_t)2 * SPAN * HH; nbase = 0; NBrows = NPAD; out = W1simT; bk64 = true; }
    ldin = HH; Cin = HH; xt = NPAD / 32;
  }
  {
    int bx = idx % xt, by = idx / xt;
    __shared__ float tile[32][33];
    int n0 = bx * 32, p0 = by * 32;
    int tx = tid & 31, ty = tid >> 5;
    for (int i = ty; i < 32; i += 8) {
      int p = p0 + i, n = n0 + tx;
      tile[i][tx] = (n < Cin) ? in[(long)p * ldin + n] : 0.f;
    }
    __syncthreads();
    if (!bk64) {
      size_t slab = (size_t)(p0 >> 5) * NBrows * 32;
      for (int i = ty; i < 32; i += 8) {
        int n = n0 + i;
        out[slab + (size_t)(nbase + n) * 32 + tx] = f2bf(tile[tx][i]);
      }
    } else {
      int p = p0 + tx;                 // k index (0..2303)
      int c = p >> 6, kin = p & 63;
      int ls = kin >> 3, e = kin & 7;
      size_t base = (size_t)c * NPAD * 64;
      for (int i = ty; i < 32; i += 8) {
        int n = n0 + i;
        int ps = ls ^ (n & 7);
        out[base + (size_t)n * 64 + ps * 8 + e] = f2bf(tile[tx][i]);
      }
    }
  }
}

// ---------------------------------------------------------------------------
// K1: hybrid doc + token attention logits
// ---------------------------------------------------------------------------
__global__ __launch_bounds__(256) void hybrid_attn_k(
    const float* __restrict__ doc, const float* __restrict__ doc1,
    const float* __restrict__ attn_w, const float* __restrict__ attn_b,
    float* __restrict__ hybrid, float* __restrict__ tok_attn)
{
  int w = blockIdx.x;
  int tid = threadIdx.x;
  float part = 0.f;
  for (int d = tid; d < DD; d += 256) {
    float h = 0.5f * doc[(long)w * DD + d] + 0.5f * doc1[(long)w * DD + d];
    hybrid[(long)w * DD + d] = h;
    part += h * attn_w[d];
  }
  for (int off = 32; off > 0; off >>= 1) part += __shfl_down(part, off, 64);
  __shared__ float ws4[4];
  if ((tid & 63) == 0) ws4[tid >> 6] = part;
  __syncthreads();
  if (tid == 0) tok_attn[w] = ws4[0] + ws4[1] + ws4[2] + ws4[3] + attn_b[0];
}

// ---------------------------------------------------------------------------
// K2: span embeddings -> se_bf [KK][SPAN] bf16
// ---------------------------------------------------------------------------
__global__ __launch_bounds__(256) void span_emb_k(
    const float* __restrict__ doc, const float* __restrict__ hybrid,
    const float* __restrict__ tok_attn, const int* __restrict__ starts,
    const int* __restrict__ ends, ushort* __restrict__ se_bf)
{
  int k = blockIdx.x;
  int s = starts[k], e = ends[k];
  int len = e - s + 1;  // <= 30
  int tid = threadIdx.x;
  __shared__ float p_s[32];
  if (tid < 32) {
    float v = (tid < len) ? tok_attn[s + tid] : -INFINITY;
    float m = v;
    for (int msk = 16; msk >= 1; msk >>= 1) m = fmaxf(m, __shfl_xor(m, msk, 32));
    float pe = (tid < len) ? expf(v - m) : 0.f;
    float Z = pe;
    for (int msk = 16; msk >= 1; msk >>= 1) Z += __shfl_xor(Z, msk, 32);
    p_s[tid] = pe / Z;
  }
  __syncthreads();
  for (int d = tid; d < DD; d += 256) {
    float h = 0.f;
    for (int t = 0; t < len; ++t) h += p_s[t] * hybrid[(long)(s + t) * DD + d];
    se_bf[(long)k * SPAN + d]          = f2bf(doc[(long)s * DD + d]);
    se_bf[(long)k * SPAN + DD + d]     = f2bf(doc[(long)e * DD + d]);
    se_bf[(long)k * SPAN + 2 * DD + d] = f2bf(h);
  }
}

// ---------------------------------------------------------------------------
// K3: combined NT GEMM, 64x128 tiles. A = se_bf shared; routed epilogue
// [src | Ptgt+b1 | Pant]. B via DMA, swizzled unpadded. (unchanged)
// ---------------------------------------------------------------------------
__global__ __launch_bounds__(256) void gemm_combined_k(
    const ushort* __restrict__ A, const ushort* __restrict__ B,
    const float* __restrict__ coarse_b, const float* __restrict__ b1,
    ushort* __restrict__ src_bf, float* __restrict__ Ptgt,
    float* __restrict__ Pant)
{
  __shared__ __align__(16) ushort As[64 * 40];
  __shared__ __align__(16) ushort Bs[128 * 32];
  int tid = threadIdx.x;
  int m0 = blockIdx.x * 64, n0 = blockIdx.y * 128;
  int lane = tid & 63, wid = tid >> 6;
  int quad = lane >> 4, lr = lane & 15;
  int wm = (wid & 1) << 5, wn = (wid >> 1) << 6;
  int arow = tid >> 2, aq = tid & 3;     // A: 64 rows, 4 lanes each
  int gofs[2];
#pragma unroll
  for (int t = 0; t < 2; ++t) {
    int S = t * 256 + tid;
    int r = S >> 2, p = S & 3;
    int q = p ^ ((r >> 1) & 3);
    gofs[t] = (n0 + r) * 32 + q * 8;
  }
  f32x4 acc[2][4] = {};
  for (int k0 = 0; k0 < SPAN; k0 += 32) {
    uint4 a0 = *(const uint4*)(A + (size_t)(m0 + arow) * SPAN + k0 + aq * 8);
    __syncthreads();
    const ushort* sb = B + (size_t)(k0 >> 5) * (NBIG * 32);
    dma16(sb + gofs[0], &Bs[(size_t)(0 * 256 + tid) * 8]);
    dma16(sb + gofs[1], &Bs[(size_t)(1 * 256 + tid) * 8]);
    *(uint4*)&As[arow * 40 + aq * 8] = a0;
    __syncthreads();
    bf16x8 af[2], bfr[4];
#pragma unroll
    for (int mi = 0; mi < 2; ++mi)
      af[mi] = *(const bf16x8*)&As[(wm + mi * 16 + lr) * 40 + quad * 8];
#pragma unroll
    for (int ni = 0; ni < 4; ++ni) {
      int r = wn + ni * 16 + lr;
      int p = quad ^ ((r >> 1) & 3);
      bfr[ni] = *(const bf16x8*)&Bs[r * 32 + p * 8];
    }
#pragma unroll
    for (int mi = 0; mi < 2; ++mi)
#pragma unroll
      for (int ni = 0; ni < 4; ++ni)
        acc[mi][ni] = __builtin_amdgcn_mfma_f32_16x16x32_bf16(
            af[mi], bfr[ni], acc[mi][ni], 0, 0, 0);
  }
#pragma unroll
  for (int mi = 0; mi < 2; ++mi)
#pragma unroll
    for (int ni = 0; ni < 4; ++ni) {
      f32x4 c = acc[mi][ni];
#pragma unroll
      for (int reg = 0; reg < 4; ++reg) {
        int gm = m0 + wm + mi * 16 + quad * 4 + reg;
        int g = n0 + wn + ni * 16 + lr;
        float v = c[reg];
        if (g < 2304) {
          src_bf[(size_t)gm * SPAN + g] = f2bf(v + coarse_b[g]);
        } else if (g < 3328) {
          int n = g - 2304;
          if (n < HH) Ptgt[(size_t)gm * HH + n] = v + b1[n];  // b1 folded in
        } else {
          int n = g - 3328;
          if (n < HH) Pant[(size_t)gm * HH + n] = v;
        }
      }
    }
}

// ---------------------------------------------------------------------------
// K4: fast GEMM (src @ se^T), 64x64 tiles, fused epilogue (unchanged)
// ---------------------------------------------------------------------------
__global__ __launch_bounds__(256) void gemm_fast_k(
    const ushort* __restrict__ A, const ushort* __restrict__ B,
    const float* __restrict__ ms, const float* __restrict__ dist_score,
    float* __restrict__ fast)
{
  __shared__ __align__(16) ushort As[64 * 40];
  __shared__ __align__(16) ushort Bs[64 * 40];
  int tid = threadIdx.x;
  int m0 = blockIdx.x * 64, n0 = blockIdx.y * 64;
  int lane = tid & 63, wid = tid >> 6;
  int quad = lane >> 4, lr = lane & 15;
  int wm = (wid & 1) << 5, wn = (wid >> 1) << 5;
  int row = tid >> 2, aq = tid & 3;
  const ushort* ga = A + (size_t)(m0 + row) * SPAN + aq * 8;
  const ushort* gb = B + (size_t)(n0 + row) * SPAN + aq * 8;
  f32x4 acc[2][2] = {};
  for (int k0 = 0; k0 < SPAN; k0 += 32) {
    uint4 a0 = *(const uint4*)(ga + k0);
    uint4 b0 = *(const uint4*)(gb + k0);
    __syncthreads();
    *(uint4*)&As[row * 40 + aq * 8] = a0;
    *(uint4*)&Bs[row * 40 + aq * 8] = b0;
    __syncthreads();
    bf16x8 af[2], bfr[2];
#pragma unroll
    for (int mi = 0; mi < 2; ++mi)
      af[mi] = *(const bf16x8*)&As[(wm + mi * 16 + lr) * 40 + quad * 8];
#pragma unroll
    for (int ni = 0; ni < 2; ++ni)
      bfr[ni] = *(const bf16x8*)&Bs[(wn + ni * 16 + lr) * 40 + quad * 8];
#pragma unroll
    for (int mi = 0; mi < 2; ++mi)
#pragma unroll
      for (int ni = 0; ni < 2; ++ni)
        acc[mi][ni] = __builtin_amdgcn_mfma_f32_16x16x32_bf16(
            af[mi], bfr[ni], acc[mi][ni], 0, 0, 0);
  }
#pragma unroll
  for (int mi = 0; mi < 2; ++mi)
#pragma unroll
    for (int ni = 0; ni < 2; ++ni) {
      f32x4 c = acc[mi][ni];
#pragma unroll
      for (int reg = 0; reg < 4; ++reg) {
        int gm = m0 + wm + mi * 16 + quad * 4 + reg;
        int gn = n0 + wn + ni * 16 + lr;
        float v;
        if (gn < gm) {
          v = c[reg] + ms[gm] + ms[gn] + dist_score[bucketd(gm - gn)];
        } else {
          v = -INFINITY;
        }
        fast[(size_t)gm * KK + gn] = v;
      }
    }
}

// ---------------------------------------------------------------------------
// K5: exact top-50 per row (descending, ties -> lower index)
// ---------------------------------------------------------------------------
__global__ __launch_bounds__(256) void topk_k(
    const float* __restrict__ fast, float* __restrict__ top_fast,
    int* __restrict__ row_j, int* __restrict__ row_bucket)
{
  __shared__ float vals[KK];
  __shared__ float wbv[4];
  __shared__ int wbi[4];
  int k = blockIdx.x;
  int tid = threadIdx.x;
  for (int j = tid; j < KK; j += 256) vals[j] = fast[(long)k * KK + j];
  __syncthreads();
  const float NANF = __uint_as_float(0x7fc00000u);
  for (int it = 0; it < CC; ++it) {
    float bv = -INFINITY;
    int bi = 1 << 30;
    for (int j = tid; j < KK; j += 256) {
      float v = vals[j];
      if (v > bv || (v == bv && j < bi)) { bv = v; bi = j; }
    }
    for (int off = 32; off > 0; off >>= 1) {
      float ov = __shfl_down(bv, off, 64);
      int oi = __shfl_down(bi, off, 64);
      if (ov > bv || (ov == bv && oi < bi)) { bv = ov; bi = oi; }
    }
    if ((tid & 63) == 0) { wbv[tid >> 6] = bv; wbi[tid >> 6] = bi; }
    __syncthreads();
    if (tid == 0) {
      for (int w = 1; w < 4; ++w) {
        float ov = wbv[w]; int oi = wbi[w];
        if (ov > bv || (ov == bv && oi < bi)) { bv = ov; bi = oi; }
      }
      int r = k * CC + it;
      top_fast[r] = bv;
      row_j[r] = bi;
      row_bucket[r] = bucketd(k - bi);
      vals[bi] = NANF;
    }
    __syncthreads();
  }
}

// ---------------------------------------------------------------------------
// K5.5: sim-product precompute -> AsimT [36 ksteps][PROWS][64] bf16,
// bank-swizzle baked into DRAM (phys slot ps holds logical ls = ps ^ (r&7))
// so the pair kernel's global_load_lds is perfectly linear.
// ---------------------------------------------------------------------------
__global__ __launch_bounds__(256) void prod_k(
    const ushort* __restrict__ se_bf, const int* __restrict__ row_j,
    ushort* __restrict__ AsimT)
{
  int u = blockIdx.x * 256 + threadIdx.x;  // < 36 * PROWS * 8 = 11,059,200
  int ls = u & 7;                          // logical 16B k-slot
  int v = u >> 3;
  int c = v / PROWS;                       // kstep 0..35
  int r = v - c * PROWS;                   // pair row
  int kidx = r / CC;
  int j = row_j[r];
  int koff = c * 64 + ls * 8;
  uint4 a = *(const uint4*)(se_bf + (size_t)kidx * SPAN + koff);
  uint4 b = *(const uint4*)(se_bf + (size_t)j * SPAN + koff);
  int ps = ls ^ (r & 7);
  *(uint4*)(AsimT + ((size_t)c * PROWS + r) * 64 + ps * 8) = pkmul4(a, b);
}

// ---------------------------------------------------------------------------
// K6: pair GEMM — 8-phase schedule (T2+T3+T4+T5 port, plain HIP).
// BM=BN=256, BK=64, 8 waves (2M x 4N), dbuf LDS 128KB, both operands via
// linear global_load_lds from pre-swizzled DRAM. Per K-step, 4 phases:
//   p0: read A-lo(8)+B-lo(4) | issue B(u+1)->other buf | 16 MFMA
//   p1: read B-hi(4)                                   | 16 MFMA
//   p2: read A-hi(8)                                   | 16 MFMA
//   p3: issue A(u+2)->this buf (A last read at p2)     | 16 MFMA | vmcnt(4)
// Counted vmcnt(4) at the K-step boundary keeps the newest A-stage in
// flight (never drain to 0 in steady state). Raw s_barrier + asm waitcnts
// + sched_barrier(0) fences (rule #18/#21). setprio(1) around MFMA (T5).
// ---------------------------------------------------------------------------
#define BM 256
#define BN 256
#define BK 64
#define KST 36   // SPAN / BK

#define PH_MID \
  __builtin_amdgcn_sched_barrier(0); \
  __builtin_amdgcn_s_barrier(); \
  asm volatile("s_waitcnt lgkmcnt(0)" ::: "memory"); \
  __builtin_amdgcn_sched_barrier(0); \
  __builtin_amdgcn_s_setprio(1)

#define PH_END \
  __builtin_amdgcn_s_setprio(0); \
  __builtin_amdgcn_sched_barrier(0); \
  __builtin_amdgcn_s_barrier(); \
  __builtin_amdgcn_sched_barrier(0)

__global__ __launch_bounds__(512, 2) void pair_mfma_k(
    const ushort* __restrict__ AsimT, const ushort* __restrict__ W1simT,
    const int* __restrict__ row_j, const int* __restrict__ row_bucket,
    const float* __restrict__ Ptgt, const float* __restrict__ Pant,
    const float* __restrict__ Pdist, const float* __restrict__ w2,
    float* __restrict__ slow)
{
  __shared__ __align__(16) ushort As[2][BM * BK];   // 2 x 32KB
  __shared__ __align__(16) ushort Bs[2][BN * BK];   // 2 x 32KB
  int tid = threadIdx.x;                 // 0..511
  // XCD swizzle: 600 blocks = 8 XCDs x 75; n fastest within an XCD chunk
  int b = blockIdx.x;
  int t = (b & 7) * 75 + (b >> 3);       // bijective on [0,600)
  int m0 = (t >> 2) * BM;                // 0..149 m-tiles
  int n0 = (t & 3) * BN;                 // 4 n-tiles
  int lane = tid & 63, wid = tid >> 6;   // 8 waves
  int quad = lane >> 4, lr = lane & 15;
  int wm = (wid >> 2) << 7;              // 0 / 128
  int wn = (wid & 3) << 6;               // 0 / 64 / 128 / 192

  const ushort* gA = AsimT + (size_t)m0 * BK + (size_t)tid * 8;
  const ushort* gB = W1simT + (size_t)n0 * BK + (size_t)tid * 8;
  const size_t ASTRIDE = (size_t)PROWS * BK;
  const size_t BSTRIDE = (size_t)NPAD * BK;

#define STAGE_A(s, bi) do { \
    const ushort* g_ = gA + (size_t)(s) * ASTRIDE; \
    ushort* l_ = &As[bi][tid * 8]; \
    dma16(g_, l_);                 dma16(g_ + 4096, l_ + 4096); \
    dma16(g_ + 8192, l_ + 8192);   dma16(g_ + 12288, l_ + 12288); \
  } while (0)
#define STAGE_B(s, bi) do { \
    const ushort* g_ = gB + (size_t)(s) * BSTRIDE; \
    ushort* l_ = &Bs[bi][tid * 8]; \
    dma16(g_, l_);                 dma16(g_ + 4096, l_ + 4096); \
    dma16(g_ + 8192, l_ + 8192);   dma16(g_ + 12288, l_ + 12288); \
  } while (0)
#define READ_A(AF, MH) do { \
    _Pragma("unroll") for (int mi = 0; mi < 4; ++mi) { \
      int row_ = wm + (MH) * 64 + mi * 16 + lr; \
      int rx_ = row_ & 7; \
      _Pragma("unroll") for (int kh = 0; kh < 2; ++kh) { \
        int ps_ = (kh * 4 + quad) ^ rx_; \
        AF[mi][kh] = *(const bf16x8*)&As[buf][row_ * 64 + ps_ * 8]; } } \
  } while (0)
#define READ_B(BF, NH) do { \
    _Pragma("unroll") for (int ni = 0; ni < 2; ++ni) { \
      int row_ = wn + (NH) * 32 + ni * 16 + lr; \
      int rx_ = row_ & 7; \
      _Pragma("unroll") for (int kh = 0; kh < 2; ++kh) { \
        int ps_ = (kh * 4 + quad) ^ rx_; \
        BF[ni][kh] = *(const bf16x8*)&Bs[buf][row_ * 64 + ps_ * 8]; } } \
  } while (0)
#define QMFMA(MH, NH, AF, BF) do { \
    _Pragma("unroll") for (int kh = 0; kh < 2; ++kh) \
      _Pragma("unroll") for (int ni = 0; ni < 2; ++ni) \
        _Pragma("unroll") for (int mi = 0; mi < 4; ++mi) \
          acc[(MH)*4 + mi][(NH)*2 + ni] = __builtin_amdgcn_mfma_f32_16x16x32_bf16( \
              AF[mi][kh], BF[ni][kh], acc[(MH)*4 + mi][(NH)*2 + ni], 0, 0, 0); \
  } while (0)

  f32x4 acc[8][4] = {};
  // prologue: stage K-step 0 (A,B) -> buf0, A of K-step 1 -> buf1 (12 loads)
  STAGE_A(0, 0);
  STAGE_B(0, 0);
  STAGE_A(1, 1);
  asm volatile("s_waitcnt vmcnt(4)" ::: "memory");   // K-step 0 landed
  __builtin_amdgcn_s_barrier();
  __builtin_amdgcn_sched_barrier(0);

  bf16x8 af[4][2], bl[2][2], bh[2][2];
  for (int u = 0; u < KST; ++u) {
    int buf = u & 1;
    // ---- phase 0: A-lo + B-lo reads; issue B(u+1) -> buf^1 ----
    READ_A(af, 0);
    READ_B(bl, 0);
    if (u + 1 < KST) STAGE_B(u + 1, buf ^ 1);
    PH_MID;
    QMFMA(0, 0, af, bl);
    PH_END;
    // ---- phase 1: B-hi reads ----
    READ_B(bh, 1);
    PH_MID;
    QMFMA(0, 1, af, bh);
    PH_END;
    // ---- phase 2: A-hi reads ----
    READ_A(af, 1);
    PH_MID;
    QMFMA(1, 0, af, bl);
    PH_END;
    // ---- phase 3: issue A(u+2) -> this buf (A region free after p2) ----
    if (u + 2 < KST) STAGE_A(u + 2, buf);
    PH_MID;
    QMFMA(1, 1, af, bh);
    __builtin_amdgcn_s_setprio(0);
    __builtin_amdgcn_sched_barrier(0);
    // K-step boundary: counted wait — newest A-stage stays in flight
    if (u < KST - 2) asm volatile("s_waitcnt vmcnt(4)" ::: "memory");
    else             asm volatile("s_waitcnt vmcnt(0)" ::: "memory");
    __builtin_amdgcn_s_barrier();
    __builtin_amdgcn_sched_barrier(0);
  }

  // ---- epilogue: fused bias/ReLU/w2-dot + 16-lane reduce + atomicAdd ----
  int nn[4]; float w2r[4]; bool nv[4];
#pragma unroll
  for (int ni = 0; ni < 4; ++ni) {
    nn[ni] = n0 + wn + ni * 16 + lr;
    nv[ni] = nn[ni] < HH;
    w2r[ni] = nv[ni] ? w2[nn[ni]] : 0.f;
  }
#pragma unroll
  for (int mg = 0; mg < 8; ++mg) {
#pragma unroll
    for (int reg = 0; reg < 4; ++reg) {
      int grow = m0 + wm + mg * 16 + quad * 4 + reg;
      int kk = grow / CC;
      int jj = row_j[grow], bb = row_bucket[grow];
      float s = 0.f;
#pragma unroll
      for (int ni = 0; ni < 4; ++ni) {
        if (nv[ni]) {
          float h = acc[mg][ni][reg] + Ptgt[(size_t)kk * HH + nn[ni]] +
                    Pant[(size_t)jj * HH + nn[ni]] +
                    Pdist[(size_t)bb * HH + nn[ni]];
          s += fmaxf(h, 0.f) * w2r[ni];
        }
      }
      s += __shfl_xor(s, 1); s += __shfl_xor(s, 2);
      s += __shfl_xor(s, 4); s += __shfl_xor(s, 8);
      if (lr == 0) atomicAdd(&slow[grow], s);
    }
  }
#undef STAGE_A
#undef STAGE_B
#undef READ_A
#undef READ_B
#undef QMFMA
}

// ---------------------------------------------------------------------------
// K7: finalize (-inf -> -1e30)
// ---------------------------------------------------------------------------
__global__ void finalize_k(const float* __restrict__ slow,
                           const float* __restrict__ top_fast,
                           const float* __restrict__ b2, float* __restrict__ out)
{
  int t = blockIdx.x * 256 + threadIdx.x;
  if (t >= KK * (CC + 1)) return;
  int k = t / (CC + 1), col = t % (CC + 1);
  if (col == 0) {
    out[t] = 0.f;
  } else {
    int r = k * CC + col - 1;
    float v = slow[r] + b2[0] + top_fast[r];
    if (!isfinite(v)) v = -1.0e30f;
    out[t] = v;
  }
}

// ---------------------------------------------------------------------------
extern "C" void kernel_launch(void* const* d_in, const int* in_sizes, int n_in,
                              void* d_out, int out_size, void* d_ws, size_t ws_size,
                              hipStream_t stream)
{
  const float* doc        = (const float*)d_in[0];
  const float* doc1       = (const float*)d_in[1];
  const int*   starts     = (const int*)d_in[2];
  const int*   ends       = (const int*)d_in[3];
  const float* ms         = (const float*)d_in[4];
  const float* attn_w     = (const float*)d_in[5];
  const float* attn_b     = (const float*)d_in[6];
  const float* coarse_w   = (const float*)d_in[7];
  const float* coarse_b   = (const float*)d_in[8];
  const float* dist_prior = (const float*)d_in[9];
  const float* dist_w     = (const float*)d_in[10];
  const float* dist_b     = (const float*)d_in[11];
  const float* top_dist   = (const float*)d_in[12];
  const float* W1         = (const float*)d_in[13];
  const float* b1         = (const float*)d_in[14];
  const float* w2         = (const float*)d_in[15];
  const float* b2         = (const float*)d_in[16];
  float* out = (float*)d_out;

  char* ws = (char*)d_ws;
  size_t off = 0;
  auto alloc = [&](size_t bytes) { void* p = ws + off; off = (off + bytes + 1023) & ~(size_t)1023; return p; };
  // --- persistent (live at/after prod_k) ---
  ushort* se_bf      = (ushort*)alloc((size_t)KK * SPAN * 2 + 4096);
  float*  Ptgt       = (float*)alloc((size_t)KK * HH * 4);
  float*  Pant       = (float*)alloc((size_t)KK * HH * 4);
  float*  Pdist      = (float*)alloc((size_t)10 * HH * 4);
  float*  dist_score = (float*)alloc(64);
  float*  top_fast   = (float*)alloc((size_t)KK * CC * 4);
  int*    row_j      = (int*)alloc((size_t)KK * CC * 4);
  int*    row_bucket = (int*)alloc((size_t)KK * CC * 4);
  float*  slow       = (float*)alloc((size_t)KK * CC * 4);
  ushort* W1simT     = (ushort*)alloc((size_t)NPAD * SPAN * 2 + 4096);   // [36][NPAD][64] swizzled
  // --- transient region (dead before prod_k runs) overlaid with AsimT ---
  size_t ovl = off;
  float*  hybrid     = (float*)alloc((size_t)WTOK * DD * 4);
  float*  tok_attn   = (float*)alloc((size_t)WTOK * 4);
  ushort* src_bf     = (ushort*)alloc((size_t)KK * SPAN * 2 + 4096);
  float*  fast       = (float*)alloc((size_t)KK * KK * 4);
  ushort* BigT       = (ushort*)alloc((size_t)NBIG * SPAN * 2 + 4096);   // k-tiled [72][NBIG][32]
  ushort* AsimT      = (ushort*)(ws + ovl);   // [36][PROWS][64] swizzled, ~177 MB
  (void)ws_size; (void)in_sizes; (void)n_in; (void)out_size;

  // 1. fused prep: transposes + dist setup + slow init
  prep_k<<<PB_TOTAL, 256, 0, stream>>>(coarse_w, W1, dist_prior, dist_w,
                                       dist_b, top_dist, BigT, W1simT,
                                       dist_score, Pdist, slow);
  // 2. hybrid + token attention
  hybrid_attn_k<<<WTOK, 256, 0, stream>>>(doc, doc1, attn_w, attn_b, hybrid, tok_attn);
  // 3. span embeddings
  span_emb_k<<<KK, 256, 0, stream>>>(doc, hybrid, tok_attn, starts, ends, se_bf);
  // 4. src_bf / Ptgt(+b1) / Pant in one launch (shared A), 64x128 tiles
  {
    dim3 g(KK / 64, NBIG / 128);
    gemm_combined_k<<<g, 256, 0, stream>>>(se_bf, BigT, coarse_b, b1,
                                           src_bf, Ptgt, Pant);
  }
  // 5. fast = src @ se^T with fused epilogue, 64x64 tiles
  {
    dim3 g(KK / 64, KK / 64);
    gemm_fast_k<<<g, 256, 0, stream>>>(src_bf, se_bf, ms, dist_score, fast);
  }
  // 6. top-50
  topk_k<<<KK, 256, 0, stream>>>(fast, top_fast, row_j, row_bucket);
  // 6.5 sim-product precompute (swizzled layout)
  prod_k<<<(36 * PROWS * 8) / 256, 256, 0, stream>>>(se_bf, row_j, AsimT);
  // 7. pair GEMM, 8-phase schedule, 600 blocks x 512 threads
  pair_mfma_k<<<(PROWS / BM) * (NPAD / BN), 512, 0, stream>>>(
      AsimT, W1simT, row_j, row_bucket, Ptgt, Pant, Pdist, w2, slow);
  // 8. output
  finalize_k<<<(KK * (CC + 1) + 255) / 256, 256, 0, stream>>>(slow, top_fast, b2, out);
}